// Round 14
// baseline (524.135 us; speedup 1.0000x reference)
//
#include <hip/hip_runtime.h>
#include <hip/hip_bf16.h>

// DigitCaps dynamic routing. Output fp32.
// R14: 5-dispatch structure. R13 showed ~9us/slot x 11 slots dominates.
// F(iter_kernel): block = (mb: 64 b-rows, o: ONE out-capsule) — per-o softmax
// is block-local (o == one MFMA n-tile!), B-frags built on the fly from W
// (packed bf16 cvt), full-K GEMM, in-register squash -> vB/out. No s_part,
// no Bs, no counters, no atomics. A(agg_kernel): R13-verified aggemm with
// full K=512 inside, writes u_t[o][i] transposed for F's reads.
// Chain: F0 -> A -> F1 -> A -> F2(out).
#define B 512
#define IC 1152
#define QD 8
#define OD 10
#define PD 16
#define KD (IC * QD)   // 9216
#define NKB (KD / 32)  // 288
#define IO (IC * OD)   // 11520

typedef short bf16x8 __attribute__((ext_vector_type(8)));
typedef float f32x4 __attribute__((ext_vector_type(4)));

__device__ __forceinline__ short f2bf(float f) {
  union { float f; unsigned u; } x;
  x.f = f;
  unsigned r = x.u + 0x7FFFu + ((x.u >> 16) & 1u);  // RNE
  return (short)(r >> 16);
}
__device__ __forceinline__ unsigned pkbf(float a, float b) {
  union { __hip_bfloat162 h; unsigned u; } c;
  c.h = __float22bfloat162_rn(make_float2(a, b));  // v_cvt_pk_bf16_f32 (RNE)
  return c.u;
}

// ---- F: per (mb,o) block: softmax c_:o, s-GEMM (64b x 16p x K9216), squash.
// mode 0: c uniform. mode 1: bij = u_t (mb==0 persists bijA). mode 2: bij = bijA + u_t.
// blockIdx = o*8 + mb  -> same-mb blocks land on one XCD (x-slice L2-resident).
__global__ __launch_bounds__(256) void iter_kernel(const float* __restrict__ x,
                                                   const float* __restrict__ W,
                                                   const float* __restrict__ u_t,
                                                   float* __restrict__ bijA,
                                                   short* __restrict__ vB,
                                                   float* __restrict__ out,
                                                   int mode) {
  __shared__ float cS[IC];
  __shared__ float redA[4], redB[4];
  const int tid = threadIdx.x;
  const int mb = blockIdx.x & 7, o = blockIdx.x >> 3;
  const int wave = tid >> 6, lane = tid & 63;
  const int ln = lane & 15, quad = lane >> 4;

  float inv = 0.f;
  if (mode != 0) {
    float lm = -1e30f;
#pragma unroll
    for (int k = 0; k < 5; ++k) {
      const int i = tid + k * 256;
      if (i < IC) {
        float t = u_t[o * IC + i];
        if (mode == 2) t += bijA[o * IC + i];
        if (mode == 1 && mb == 0) bijA[o * IC + i] = t;
        cS[i] = t;
        lm = fmaxf(lm, t);
      }
    }
#pragma unroll
    for (int s = 1; s < 64; s <<= 1) lm = fmaxf(lm, __shfl_xor(lm, s));
    if (lane == 0) redA[wave] = lm;
    __syncthreads();
    const float mx = fmaxf(fmaxf(redA[0], redA[1]), fmaxf(redA[2], redA[3]));
    float ls = 0.f;
#pragma unroll
    for (int k = 0; k < 5; ++k) {
      const int i = tid + k * 256;
      if (i < IC) {
        const float e = __expf(cS[i] - mx);
        cS[i] = e;
        ls += e;
      }
    }
#pragma unroll
    for (int s = 1; s < 64; s <<= 1) ls += __shfl_xor(ls, s);
    if (lane == 0) redB[wave] = ls;
    __syncthreads();
    inv = 1.f / (redB[0] + redB[1] + redB[2] + redB[3]);
  }

  // GEMM: wave covers 16 b-rows (m0..m0+15) x 16 p (this o), K = 9216.
  const int m0 = mb * 64 + wave * 16;
  const float* arow = x + (size_t)(m0 + ln) * KD + quad * 8;  // A row = lane&15 [R13-proven]
  const float* wrow = W + (o * PD + ln) * QD;                 // + i*1280
  const float cu = 1.0f / (float)IC;
  f32x4 acc0 = {}, acc1 = {};
#pragma unroll 2
  for (int kb = 0; kb < NKB; kb += 2) {
    {
      const int i = kb * 4 + quad;
      const float ci = mode ? cS[i] * inv : cu;
      const f32x4 a0 = *(const f32x4*)(arow + (size_t)kb * 32);
      const f32x4 a1 = *(const f32x4*)(arow + (size_t)kb * 32 + 4);
      const f32x4 w0 = *(const f32x4*)(wrow + (size_t)i * 1280);
      const f32x4 w1 = *(const f32x4*)(wrow + (size_t)i * 1280 + 4);
      uint4 ap, bp;
      ap.x = pkbf(a0[0], a0[1]); ap.y = pkbf(a0[2], a0[3]);
      ap.z = pkbf(a1[0], a1[1]); ap.w = pkbf(a1[2], a1[3]);
      bp.x = pkbf(ci * w0[0], ci * w0[1]); bp.y = pkbf(ci * w0[2], ci * w0[3]);
      bp.z = pkbf(ci * w1[0], ci * w1[1]); bp.w = pkbf(ci * w1[2], ci * w1[3]);
      acc0 = __builtin_amdgcn_mfma_f32_16x16x32_bf16(*(bf16x8*)&ap, *(bf16x8*)&bp, acc0, 0, 0, 0);
    }
    {
      const int i = (kb + 1) * 4 + quad;
      const float ci = mode ? cS[i] * inv : cu;
      const f32x4 a0 = *(const f32x4*)(arow + (size_t)(kb + 1) * 32);
      const f32x4 a1 = *(const f32x4*)(arow + (size_t)(kb + 1) * 32 + 4);
      const f32x4 w0 = *(const f32x4*)(wrow + (size_t)i * 1280);
      const f32x4 w1 = *(const f32x4*)(wrow + (size_t)i * 1280 + 4);
      uint4 ap, bp;
      ap.x = pkbf(a0[0], a0[1]); ap.y = pkbf(a0[2], a0[3]);
      ap.z = pkbf(a1[0], a1[1]); ap.w = pkbf(a1[2], a1[3]);
      bp.x = pkbf(ci * w0[0], ci * w0[1]); bp.y = pkbf(ci * w0[2], ci * w0[3]);
      bp.z = pkbf(ci * w1[0], ci * w1[1]); bp.w = pkbf(ci * w1[2], ci * w1[3]);
      acc1 = __builtin_amdgcn_mfma_f32_16x16x32_bf16(*(bf16x8*)&ap, *(bf16x8*)&bp, acc1, 0, 0, 0);
    }
  }
  const f32x4 acc = acc0 + acc1;
  // squash in-register: C/D row = quad*4+r (b), col = ln (p) [m89-verified].
#pragma unroll
  for (int r = 0; r < 4; ++r) {
    float sq = acc[r] * acc[r];
    sq += __shfl_xor(sq, 1); sq += __shfl_xor(sq, 2);
    sq += __shfl_xor(sq, 4); sq += __shfl_xor(sq, 8);   // sum over 16 p-lanes
    const float norm = sqrtf(sq + 1e-8f);
    const float val = acc[r] * (sq / ((1.f + sq) * norm));
    const int b = m0 + quad * 4 + r;
    if (mode == 2) {
      out[((size_t)b * OD + o) * PD + ln] = val;
    } else {
      vB[((size_t)(b >> 5) * 160 + o * PD + ln) * 32 + (b & 31)] = f2bf(val);
    }
  }
}

// ---- A: u_t[o][i] = (1/B) sum_{q,p} W[i,o,p,q] G[(i,q),(o,p)], G = x^T v
// via MFMA, full K=512 (4 staged chunks). Block = 64 (i,q)-rows (8 i), 144 blocks.
__global__ __launch_bounds__(256) void agg_kernel(const float* __restrict__ x,
                                                  const float* __restrict__ W,
                                                  const short* __restrict__ vB,
                                                  float* __restrict__ u_t) {
  __shared__ __align__(16) short Abuf[16 * 64 * 8];  // 16 KB
  const int tid = threadIdx.x;
  const int ig8 = blockIdx.x;
  const int mt = tid >> 6, lane = tid & 63;
  const int ln = lane & 15, quad = lane >> 4;
  f32x4 acc[10] = {};
  for (int kq = 0; kq < 4; ++kq) {
    const int b0 = kq * 128;
    __syncthreads();
#pragma unroll
    for (int j = 0; j < 8; ++j) {  // stage x -> A-frag layout [m120-verified]
      const int idx = tid + j * 256;
      const int b = idx >> 4, f4 = idx & 15;
      const float4 vx = *(const float4*)(x + (size_t)(b0 + b) * KD + ig8 * 64 + f4 * 4);
      const int kbl = b >> 5, qk = (b & 31) >> 3, jj = b & 7;
      const int mtt = f4 >> 2, mlb = (f4 & 3) * 4;
      short* dst = Abuf + (((mtt * 4 + kbl) * 64 + qk * 16 + mlb) * 8 + jj);
      dst[0] = f2bf(vx.x); dst[8] = f2bf(vx.y); dst[16] = f2bf(vx.z); dst[24] = f2bf(vx.w);
    }
    __syncthreads();
#pragma unroll
    for (int kbb = 0; kbb < 4; ++kbb) {
      const bf16x8 af = *(const bf16x8*)(Abuf + ((mt * 4 + kbb) * 64 + lane) * 8);
      const short* bp = vB + ((size_t)((kq * 4 + kbb) * 160) + ln) * 32 + quad * 8;
#pragma unroll
      for (int nt = 0; nt < 10; ++nt) {
        const bf16x8 bf = *(const bf16x8*)(bp + nt * 512);
        acc[nt] = __builtin_amdgcn_mfma_f32_16x16x32_bf16(af, bf, acc[nt], 0, 0, 0);
      }
    }
  }
  // epilogue: contract G with W in-register [R13-proven mapping], write u_t^T
  const int i = ig8 * 8 + mt * 2 + (quad >> 1);
  const int qb = (quad & 1) * 4;
#pragma unroll
  for (int nt = 0; nt < 10; ++nt) {
    const float4 wv = *(const float4*)(W + (((size_t)i * OD + nt) * PD + ln) * QD + qb);
    float pa = acc[nt][0] * wv.x + acc[nt][1] * wv.y + acc[nt][2] * wv.z + acc[nt][3] * wv.w;
    pa += __shfl_xor(pa, 1); pa += __shfl_xor(pa, 2); pa += __shfl_xor(pa, 4);
    pa += __shfl_xor(pa, 8); pa += __shfl_xor(pa, 16);
    if ((lane & 31) == 0) u_t[(size_t)nt * IC + i] = pa * (1.0f / (float)B);
  }
}

// ---- launch: 5 dispatches ---------------------------------------------------

extern "C" void kernel_launch(void* const* d_in, const int* in_sizes, int n_in,
                              void* d_out, int out_size, void* d_ws, size_t ws_size,
                              hipStream_t stream) {
  const float* x = (const float*)d_in[0];  // [512,1152,8] fp32
  const float* W = (const float*)d_in[1];  // [1152,10,16,8] fp32
  float* out = (float*)d_out;              // [512,10,16] fp32

  // workspace: 137 KB. All buffers fully written before any read each call.
  float* ws = (float*)d_ws;
  float* u_t = ws;                 // [10][1152]
  float* bijA = u_t + IO;          // [10][1152]
  short* vB = (short*)(bijA + IO); // [16][160][32] bf16

  iter_kernel<<<80, 256, 0, stream>>>(x, W, u_t, bijA, vB, out, 0);
  agg_kernel<<<144, 256, 0, stream>>>(x, W, vB, u_t);
  iter_kernel<<<80, 256, 0, stream>>>(x, W, u_t, bijA, vB, out, 1);
  agg_kernel<<<144, 256, 0, stream>>>(x, W, vB, u_t);
  iter_kernel<<<80, 256, 0, stream>>>(x, W, u_t, bijA, vB, out, 2);
}

// Round 15
// 219.180 us; speedup vs baseline: 2.3913x; 2.3913x over previous
//
#include <hip/hip_runtime.h>
#include <hip/hip_bf16.h>

// DigitCaps dynamic routing. Output fp32.
// R15: R14's fused-F was 175us at 0.31 waves/SIMD (occupancy 3.6% — pure
// latency, the counters' verdict). Restore split-K TLP: F = (10 o x 8 mb x
// 9 K-chunks) = 720 blocks writing fp32 partials; tiny squash reduces 9 +
// squashes -> vB/out (R13-proven). A unchanged (R13/R14-verified). 8 dispatches.
#define B 512
#define IC 1152
#define QD 8
#define OD 10
#define PD 16
#define KD (IC * QD)   // 9216
#define NKB (KD / 32)  // 288
#define NCS 9          // K-chunks in F; 288/9 = 32 kb-steps each
#define KSTEPS (NKB / NCS)
#define IO (IC * OD)   // 11520
#define SOP (B * OD * PD)  // 81920

typedef short bf16x8 __attribute__((ext_vector_type(8)));
typedef float f32x4 __attribute__((ext_vector_type(4)));

__device__ __forceinline__ short f2bf(float f) {
  union { float f; unsigned u; } x;
  x.f = f;
  unsigned r = x.u + 0x7FFFu + ((x.u >> 16) & 1u);  // RNE
  return (short)(r >> 16);
}
__device__ __forceinline__ unsigned pkbf(float a, float b) {
  union { __hip_bfloat162 h; unsigned u; } c;
  c.h = __float22bfloat162_rn(make_float2(a, b));  // v_cvt_pk_bf16_f32 (RNE)
  return c.u;
}

// ---- F: block = (o, mb, cz). Redundant per-o softmax (1152 elems, cheap),
// then K=1024 GEMM chunk with B-frags built on the fly from W; fp32 partial
// out to s_part[cz][b][o*16+p]. mode 0: c uniform; 1: bij=u_t (persist at
// mb==0&&cz==0); 2: bij=bijA+u_t.
__global__ __launch_bounds__(256) void f_kernel(const float* __restrict__ x,
                                                const float* __restrict__ W,
                                                const float* __restrict__ u_t,
                                                float* __restrict__ bijA,
                                                float* __restrict__ s_part,
                                                int mode) {
  __shared__ float cS[IC];
  __shared__ float redA[4], redB[4];
  const int tid = threadIdx.x;
  const int o = blockIdx.x / 72;
  const int r72 = blockIdx.x % 72;
  const int mb = r72 / NCS, cz = r72 % NCS;
  const int wave = tid >> 6, lane = tid & 63;
  const int ln = lane & 15, quad = lane >> 4;

  float inv = 0.f;
  if (mode != 0) {
    float lm = -1e30f;
#pragma unroll
    for (int k = 0; k < 5; ++k) {
      const int i = tid + k * 256;
      if (i < IC) {
        float t = u_t[o * IC + i];
        if (mode == 2) t += bijA[o * IC + i];
        if (mode == 1 && mb == 0 && cz == 0) bijA[o * IC + i] = t;
        cS[i] = t;
        lm = fmaxf(lm, t);
      }
    }
#pragma unroll
    for (int s = 1; s < 64; s <<= 1) lm = fmaxf(lm, __shfl_xor(lm, s));
    if (lane == 0) redA[wave] = lm;
    __syncthreads();
    const float mx = fmaxf(fmaxf(redA[0], redA[1]), fmaxf(redA[2], redA[3]));
    float ls = 0.f;
#pragma unroll
    for (int k = 0; k < 5; ++k) {
      const int i = tid + k * 256;
      if (i < IC) {
        const float e = __expf(cS[i] - mx);
        cS[i] = e;
        ls += e;
      }
    }
#pragma unroll
    for (int s = 1; s < 64; s <<= 1) ls += __shfl_xor(ls, s);
    if (lane == 0) redB[wave] = ls;
    __syncthreads();
    inv = 1.f / (redB[0] + redB[1] + redB[2] + redB[3]);
  }

  // GEMM chunk: wave = 16 b-rows x 16 p (this o), K = KSTEPS*32.
  const int m0 = mb * 64 + wave * 16;
  const float* arow = x + (size_t)(m0 + ln) * KD + quad * 8;  // A[m=lane&15] [verified]
  const float* wrow = W + (o * PD + ln) * QD;                 // + i*1280
  const float cu = 1.0f / (float)IC;
  f32x4 acc0 = {}, acc1 = {};
  const int kb0 = cz * KSTEPS;
#pragma unroll 2
  for (int kk = 0; kk < KSTEPS; kk += 2) {
    {
      const int kb = kb0 + kk;
      const int i = kb * 4 + quad;
      const float ci = mode ? cS[i] * inv : cu;
      const f32x4 a0 = *(const f32x4*)(arow + (size_t)kb * 32);
      const f32x4 a1 = *(const f32x4*)(arow + (size_t)kb * 32 + 4);
      const f32x4 w0 = *(const f32x4*)(wrow + (size_t)i * 1280);
      const f32x4 w1 = *(const f32x4*)(wrow + (size_t)i * 1280 + 4);
      uint4 ap, bp;
      ap.x = pkbf(a0[0], a0[1]); ap.y = pkbf(a0[2], a0[3]);
      ap.z = pkbf(a1[0], a1[1]); ap.w = pkbf(a1[2], a1[3]);
      bp.x = pkbf(ci * w0[0], ci * w0[1]); bp.y = pkbf(ci * w0[2], ci * w0[3]);
      bp.z = pkbf(ci * w1[0], ci * w1[1]); bp.w = pkbf(ci * w1[2], ci * w1[3]);
      acc0 = __builtin_amdgcn_mfma_f32_16x16x32_bf16(*(bf16x8*)&ap, *(bf16x8*)&bp, acc0, 0, 0, 0);
    }
    {
      const int kb = kb0 + kk + 1;
      const int i = kb * 4 + quad;
      const float ci = mode ? cS[i] * inv : cu;
      const f32x4 a0 = *(const f32x4*)(arow + (size_t)kb * 32);
      const f32x4 a1 = *(const f32x4*)(arow + (size_t)kb * 32 + 4);
      const f32x4 w0 = *(const f32x4*)(wrow + (size_t)i * 1280);
      const f32x4 w1 = *(const f32x4*)(wrow + (size_t)i * 1280 + 4);
      uint4 ap, bp;
      ap.x = pkbf(a0[0], a0[1]); ap.y = pkbf(a0[2], a0[3]);
      ap.z = pkbf(a1[0], a1[1]); ap.w = pkbf(a1[2], a1[3]);
      bp.x = pkbf(ci * w0[0], ci * w0[1]); bp.y = pkbf(ci * w0[2], ci * w0[3]);
      bp.z = pkbf(ci * w1[0], ci * w1[1]); bp.w = pkbf(ci * w1[2], ci * w1[3]);
      acc1 = __builtin_amdgcn_mfma_f32_16x16x32_bf16(*(bf16x8*)&ap, *(bf16x8*)&bp, acc1, 0, 0, 0);
    }
  }
  const f32x4 acc = acc0 + acc1;
  // C/D: row = quad*4+r (b), col = ln (p)  [m89-verified]
  float* sp = s_part + (size_t)cz * SOP;
#pragma unroll
  for (int r = 0; r < 4; ++r)
    sp[(size_t)(m0 + quad * 4 + r) * 160 + o * PD + ln] = acc[r];
}

// ---- squash: reduce NCS partials + squash; emit vB (B-frag swizzle) or out.
__global__ __launch_bounds__(256) void squash_kernel(const float* __restrict__ s_part,
                                                     short* __restrict__ vB,
                                                     float* __restrict__ out,
                                                     int write_out) {
  const int t = blockIdx.x * 256 + threadIdx.x;  // < 81920, t = b*160 + n
  float sv = 0.f;
#pragma unroll
  for (int ch = 0; ch < NCS; ++ch) sv += s_part[(size_t)ch * SOP + t];
  float sq = sv * sv;
#pragma unroll
  for (int m = 1; m < 16; m <<= 1) sq += __shfl_xor(sq, m, 16);
  const float norm = sqrtf(sq + 1e-8f);
  const float val = sv * (sq / ((1.f + sq) * norm));
  if (write_out) {
    out[t] = val;
  } else {
    const int b = t / 160, n = t - b * 160;
    vB[((size_t)(b >> 5) * 160 + n) * 32 + (b & 31)] = f2bf(val);
  }
}

// ---- A: u_t[o][i] via MFMA (R13/R14-verified), full K=512 staged in 4 chunks.
__global__ __launch_bounds__(256) void agg_kernel(const float* __restrict__ x,
                                                  const float* __restrict__ W,
                                                  const short* __restrict__ vB,
                                                  float* __restrict__ u_t) {
  __shared__ __align__(16) short Abuf[16 * 64 * 8];  // 16 KB
  const int tid = threadIdx.x;
  const int ig8 = blockIdx.x;
  const int mt = tid >> 6, lane = tid & 63;
  const int ln = lane & 15, quad = lane >> 4;
  f32x4 acc[10] = {};
  for (int kq = 0; kq < 4; ++kq) {
    const int b0 = kq * 128;
    __syncthreads();
#pragma unroll
    for (int j = 0; j < 8; ++j) {  // stage x -> A-frag layout [m120-verified]
      const int idx = tid + j * 256;
      const int b = idx >> 4, f4 = idx & 15;
      const float4 vx = *(const float4*)(x + (size_t)(b0 + b) * KD + ig8 * 64 + f4 * 4);
      const int kbl = b >> 5, qk = (b & 31) >> 3, jj = b & 7;
      const int mtt = f4 >> 2, mlb = (f4 & 3) * 4;
      short* dst = Abuf + (((mtt * 4 + kbl) * 64 + qk * 16 + mlb) * 8 + jj);
      dst[0] = f2bf(vx.x); dst[8] = f2bf(vx.y); dst[16] = f2bf(vx.z); dst[24] = f2bf(vx.w);
    }
    __syncthreads();
#pragma unroll
    for (int kbb = 0; kbb < 4; ++kbb) {
      const bf16x8 af = *(const bf16x8*)(Abuf + ((mt * 4 + kbb) * 64 + lane) * 8);
      const short* bp = vB + ((size_t)((kq * 4 + kbb) * 160) + ln) * 32 + quad * 8;
#pragma unroll
      for (int nt = 0; nt < 10; ++nt) {
        const bf16x8 bf = *(const bf16x8*)(bp + nt * 512);
        acc[nt] = __builtin_amdgcn_mfma_f32_16x16x32_bf16(af, bf, acc[nt], 0, 0, 0);
      }
    }
  }
  const int i = ig8 * 8 + mt * 2 + (quad >> 1);
  const int qb = (quad & 1) * 4;
#pragma unroll
  for (int nt = 0; nt < 10; ++nt) {
    const float4 wv = *(const float4*)(W + (((size_t)i * OD + nt) * PD + ln) * QD + qb);
    float pa = acc[nt][0] * wv.x + acc[nt][1] * wv.y + acc[nt][2] * wv.z + acc[nt][3] * wv.w;
    pa += __shfl_xor(pa, 1); pa += __shfl_xor(pa, 2); pa += __shfl_xor(pa, 4);
    pa += __shfl_xor(pa, 8); pa += __shfl_xor(pa, 16);
    if ((lane & 31) == 0) u_t[(size_t)nt * IC + i] = pa * (1.0f / (float)B);
  }
}

// ---- launch: 8 dispatches ---------------------------------------------------

extern "C" void kernel_launch(void* const* d_in, const int* in_sizes, int n_in,
                              void* d_out, int out_size, void* d_ws, size_t ws_size,
                              hipStream_t stream) {
  const float* x = (const float*)d_in[0];  // [512,1152,8] fp32
  const float* W = (const float*)d_in[1];  // [1152,10,16,8] fp32
  float* out = (float*)d_out;              // [512,10,16] fp32

  // workspace ~3.2 MB; all buffers fully written before read each call
  float* ws = (float*)d_ws;
  float* s_part = ws;                        // 9*81920
  float* u_t = s_part + (size_t)NCS * SOP;   // 11520
  float* bijA = u_t + IO;                    // 11520
  short* vB = (short*)(bijA + IO);           // 16*160*32 bf16

  f_kernel<<<720, 256, 0, stream>>>(x, W, u_t, bijA, s_part, 0);
  squash_kernel<<<SOP / 256, 256, 0, stream>>>(s_part, vB, out, 0);
  agg_kernel<<<144, 256, 0, stream>>>(x, W, vB, u_t);
  f_kernel<<<720, 256, 0, stream>>>(x, W, u_t, bijA, s_part, 1);
  squash_kernel<<<SOP / 256, 256, 0, stream>>>(s_part, vB, out, 0);
  agg_kernel<<<144, 256, 0, stream>>>(x, W, vB, u_t);
  f_kernel<<<720, 256, 0, stream>>>(x, W, u_t, bijA, s_part, 2);
  squash_kernel<<<SOP / 256, 256, 0, stream>>>(s_part, vB, out, 1);
}